// Round 7
// baseline (173.950 us; speedup 1.0000x reference)
//
#include <hip/hip_runtime.h>
#include <stdint.h>

#define M_DIM 2048
#define N_DIM 4096
#define K_DIM 4096
#define NGROUP 32
#define GSIZE 128

#define RQ_UP   (127.0f / 15.0f)   // weight requant gain
#define RQ_DOWN (15.0f / 127.0f)

// ---------------------------------------------------------------------------
// R7: cut LDS traffic 25% (theory: LDS read+DMA-write contention is the real
// serialized bottleneck; 6 schedule variants all pinned at ~1845 cyc/step).
// Block 128x256, 4 waves (2Mx2N), wave tile 64x128 = 4x8 frags of 16x16x64
// i8 MFMA -> 12 ds_read_b128 per 32 MFMA (0.375/MFMA vs 0.5 before).
// 3 LDS slots x 24 KiB, depth-2 DMA prefetch (6 DMA/stage, steady vmcnt(6)),
// register double-buffer with lgkmcnt(12), ONE barrier per body.
// 1 wave/SIMD -> full 512-reg unified budget covers acc(128)+2 frag sets(96).
// LDS swizzle unchanged (verified 0 conflicts R1-R6).
// ---------------------------------------------------------------------------
#define BM 128
#define BN 256
#define KSLICE 64
#define NSLICE (K_DIM / KSLICE)    // 64
#define SLOT 24576                 // 8 KiB A + 16 KiB B

typedef __attribute__((ext_vector_type(4))) int int32x4_t;

static __device__ __forceinline__ void gl2lds16(const void* g, void* l) {
    auto gp = (const __attribute__((address_space(1))) unsigned int*)(uintptr_t)g;
    auto lp = (__attribute__((address_space(3))) unsigned int*)(uintptr_t)l;
    __builtin_amdgcn_global_load_lds(gp, lp, 16, 0, 0);
}

// bare counted waits (no "memory" clobber), pinned with sched_barrier(0)
#define WAITVM_(N) asm volatile("s_waitcnt vmcnt(" #N ")")
#define WAITVM(N)                                   \
    do {                                            \
        __builtin_amdgcn_sched_barrier(0);          \
        WAITVM_(N);                                 \
        __builtin_amdgcn_sched_barrier(0);          \
    } while (0)
#define WAITLGKM_(N) asm volatile("s_waitcnt lgkmcnt(" #N ")")
#define WAITLGKM(N)                                 \
    do {                                            \
        __builtin_amdgcn_sched_barrier(0);          \
        WAITLGKM_(N);                               \
        __builtin_amdgcn_sched_barrier(0);          \
    } while (0)
#define BARRIER()                                   \
    do {                                            \
        __builtin_amdgcn_sched_barrier(0);          \
        __builtin_amdgcn_s_barrier();               \
        __builtin_amdgcn_sched_barrier(0);          \
    } while (0)

// ---------------------------------------------------------------------------
// Fused prep (unchanged from R5/R6):
//   [0, 2048): per-token activation quant -> A8 = (q-128) int8, xscale, czp
//   [2048, ..): weight requant; rsn computed in-cluster via shfl_xor max.
// ---------------------------------------------------------------------------
#define QUANT_BLOCKS M_DIM
#define DEQ_BLOCKS ((N_DIM * K_DIM) / 8 / 256)       // 8 codes / thread

__global__ __launch_bounds__(256) void prep_kernel(
        const float* __restrict__ x,
        const int* __restrict__ qw,          // [N][K] codes 0..15 as int32
        const float* __restrict__ wsc,       // [N][32]
        const int* __restrict__ wzp,         // [N][32]
        char* __restrict__ A8,               // [M][K] int8 (q-128)
        char* __restrict__ Bt8,              // [N][K] int8 requantized
        float* __restrict__ xscale,          // [M]
        float* __restrict__ xzpc,            // [M]  = 128 - zp
        int* __restrict__ Sw)                // [N][32] group sums of Bt8
{
    const int t = threadIdx.x;
    if (blockIdx.x < QUANT_BLOCKS) {
        const int s = blockIdx.x;
        const float* xrow = x + (size_t)s * K_DIM;

        float xv[16];
        float vmin = 1e38f, vmax = -1e38f;
#pragma unroll
        for (int p = 0; p < 4; ++p) {
            float4 v = *((const float4*)(xrow + p * 1024) + t);
            xv[p*4+0] = v.x; xv[p*4+1] = v.y; xv[p*4+2] = v.z; xv[p*4+3] = v.w;
            vmin = fminf(vmin, fminf(fminf(v.x, v.y), fminf(v.z, v.w)));
            vmax = fmaxf(vmax, fmaxf(fmaxf(v.x, v.y), fmaxf(v.z, v.w)));
        }
#pragma unroll
        for (int off = 32; off > 0; off >>= 1) {
            vmin = fminf(vmin, __shfl_xor(vmin, off));
            vmax = fmaxf(vmax, __shfl_xor(vmax, off));
        }
        __shared__ float smin[4], smax[4];
        const int wave = t >> 6;
        if ((t & 63) == 0) { smin[wave] = vmin; smax[wave] = vmax; }
        __syncthreads();
        vmin = fminf(fminf(smin[0], smin[1]), fminf(smin[2], smin[3]));
        vmax = fmaxf(fmaxf(smax[0], smax[1]), fmaxf(smax[2], smax[3]));

        float sc = (vmax - vmin) / 255.0f;
        sc = fmaxf(sc, 1e-5f);
        float zp = rintf(-vmin / sc);
        zp = fminf(fmaxf(zp, 0.0f), 255.0f);
        const float inv_sc = 1.0f / sc;

#pragma unroll
        for (int p = 0; p < 4; ++p) {
            int b[4];
#pragma unroll
            for (int e = 0; e < 4; ++e) {
                float q = fminf(fmaxf(rintf(xv[p*4+e] * inv_sc) + zp, 0.0f), 255.0f);
                b[e] = (int)q - 128;
            }
            unsigned pack = (b[0] & 0xff) | ((b[1] & 0xff) << 8) |
                            ((b[2] & 0xff) << 16) | ((b[3] & 0xff) << 24);
            *(unsigned*)(A8 + (size_t)s * K_DIM + p * 1024 + t * 4) = pack;
        }
        if (t == 0) { xscale[s] = sc; xzpc[s] = 128.0f - zp; }
    } else {
        // ---- weight requant: 8 codes/thread; 16-lane cluster = 1 group ----
        const size_t base = ((size_t)(blockIdx.x - QUANT_BLOCKS) * 256 + t) * 8;
        const int n = (int)(base >> 12);          // /4096
        const int g = (int)((base >> 7) & 31);
        const int zp = wzp[n * NGROUP + g];

        // inline rsn: row max of the 32 scales across the 16-lane cluster
        const int cl = t & 15;
        float2 wp = *(const float2*)(wsc + (size_t)n * NGROUP + cl * 2);
        float smx = fmaxf(wp.x, wp.y);
#pragma unroll
        for (int off = 1; off < 16; off <<= 1)
            smx = fmaxf(smx, __shfl_xor(smx, off));
        const float factor = wsc[n * NGROUP + g] * (RQ_UP / smx);   // <= 127/15

        int4 c0 = *(const int4*)(qw + base);
        int4 c1 = *(const int4*)(qw + base + 4);
        int w[8];
        w[0] = (int)rintf((float)(c0.x - zp) * factor);
        w[1] = (int)rintf((float)(c0.y - zp) * factor);
        w[2] = (int)rintf((float)(c0.z - zp) * factor);
        w[3] = (int)rintf((float)(c0.w - zp) * factor);
        w[4] = (int)rintf((float)(c1.x - zp) * factor);
        w[5] = (int)rintf((float)(c1.y - zp) * factor);
        w[6] = (int)rintf((float)(c1.z - zp) * factor);
        w[7] = (int)rintf((float)(c1.w - zp) * factor);
        uint2 pk;
        pk.x = (w[0] & 0xff) | ((w[1] & 0xff) << 8) | ((w[2] & 0xff) << 16) | ((w[3] & 0xff) << 24);
        pk.y = (w[4] & 0xff) | ((w[5] & 0xff) << 8) | ((w[6] & 0xff) << 16) | ((w[7] & 0xff) << 24);
        *(uint2*)(Bt8 + base) = pk;

        int s8 = w[0] + w[1] + w[2] + w[3] + w[4] + w[5] + w[6] + w[7];
#pragma unroll
        for (int off = 1; off < 16; off <<= 1) s8 += __shfl_xor(s8, off);
        if ((t & 15) == 0)
            Sw[n * NGROUP + g] = s8;     // coalesced, no atomic
    }
}

// ---------------------------------------------------------------------------
// Pipelined i8 GEMM, 0.375 reads/MFMA geometry, 1 barrier/body.
// Epilogue: out[m][n] = xscale[m]*(fws[n]*iacc + czp[m]*WSf[n]) + bias[n]
// ---------------------------------------------------------------------------
__global__ __launch_bounds__(256, 1) void gemm_kernel(
        const char* __restrict__ A8,     // [M][K] int8
        const char* __restrict__ Bt8,    // [N][K] int8
        const float* __restrict__ xscale,
        const float* __restrict__ xzpc,
        const float* __restrict__ wsc,   // [N][32]
        const int* __restrict__ Sw,      // [N][32]
        const float* __restrict__ bias,  // [N]
        float* __restrict__ out)         // [M][N] f32
{
    __shared__ __align__(16) char Ls[3][SLOT];    // 72 KiB: per slot 8K A + 16K B
    __shared__ float fws_s[BN], wsf_s[BN];

    const int tid  = threadIdx.x;
    const int bn   = blockIdx.x;
    const int bm   = blockIdx.y;
    const int wave = tid >> 6;           // 0..3
    const int lane = tid & 63;
    const int wr   = wave >> 1;          // 0..1 -> 64-row band
    const int wcl  = wave & 1;           // 0..1 -> 128-col band
    const int lrow  = lane & 15;
    const int lquad = lane >> 4;         // 0..3 -> 16B k-chunk

    // --- per-column epilogue constants (all 256 threads, n = bn*256+tid) ---
    {
        const int n = bn * BN + tid;
        const int4* s4 = (const int4*)(Sw + (size_t)n * NGROUP);
        int acc = 0;
#pragma unroll
        for (int p = 0; p < 8; ++p) { int4 v = s4[p]; acc += v.x + v.y + v.z + v.w; }
        const float4* w4 = (const float4*)(wsc + (size_t)n * NGROUP);
        float s = 0.f;
#pragma unroll
        for (int p = 0; p < 8; ++p) {
            float4 w = w4[p];
            s = fmaxf(s, fmaxf(fmaxf(w.x, w.y), fmaxf(w.z, w.w)));
        }
        const float fw = s * RQ_DOWN;
        fws_s[tid] = fw;
        wsf_s[tid] = fw * (float)acc;
    }
    // drain once to a clean vmcnt/lgkm baseline for the counted waits
    __builtin_amdgcn_sched_barrier(0);
    asm volatile("s_waitcnt vmcnt(0) lgkmcnt(0)");
    __builtin_amdgcn_sched_barrier(0);

    // --- staging: gl2lds dst = uniform base + lane*16 (m104). Each DMA
    // stages 16 rows x 64 B. A: rows 0-127 (2 instr/wave); B: rows(cols)
    // 0-255 (4 instr/wave). Swizzle: chunk c of row r at slot c^((r>>1)&3).
    const char* Ab = A8  + (size_t)(bm * BM) * K_DIM;
    const char* Bb = Bt8 + (size_t)(bn * BN) * K_DIM;
    const int lsub = lane >> 2;                    // row within 16-row slab
    const int csrc = (lane & 3) ^ ((lane >> 3) & 3);
    const char* gA0 = Ab + (size_t)(wave * 16       + lsub) * K_DIM + csrc * 16;
    const char* gA1 = Ab + (size_t)(wave * 16 +  64 + lsub) * K_DIM + csrc * 16;
    const char* gB0 = Bb + (size_t)(wave * 16       + lsub) * K_DIM + csrc * 16;
    const char* gB1 = Bb + (size_t)(wave * 16 +  64 + lsub) * K_DIM + csrc * 16;
    const char* gB2 = Bb + (size_t)(wave * 16 + 128 + lsub) * K_DIM + csrc * 16;
    const char* gB3 = Bb + (size_t)(wave * 16 + 192 + lsub) * K_DIM + csrc * 16;
    const int lOF = wave * 1024;

    // --- ds_read addresses (LDS 32-bit), swizzle matches staging ---
    const int xq = (lquad ^ ((lrow >> 1) & 3)) * 16;
    const unsigned lsBase = (unsigned)(uintptr_t)&Ls[0][0];
    const unsigned aOff0 = (unsigned)((wr  * 64  + lrow) * KSLICE + xq);
    const unsigned bOff0 = (unsigned)(8192 + (wcl * 128 + lrow) * KSLICE + xq);

    int32x4_t iacc[4][8];
    const int32x4_t zi = {0, 0, 0, 0};
#pragma unroll
    for (int i = 0; i < 4; ++i)
#pragma unroll
        for (int j = 0; j < 8; ++j) iacc[i][j] = zi;

#define STAGE(t, SL) {                                                \
        const size_t k0_ = (size_t)(t) * KSLICE;                      \
        char* sb_ = &Ls[SL][0];                                       \
        gl2lds16(gA0 + k0_, sb_ + lOF);                               \
        gl2lds16(gA1 + k0_, sb_ + 4096 + lOF);                        \
        gl2lds16(gB0 + k0_, sb_ + 8192 + lOF);                        \
        gl2lds16(gB1 + k0_, sb_ + 8192 + 4096 + lOF);                 \
        gl2lds16(gB2 + k0_, sb_ + 8192 + 8192 + lOF);                 \
        gl2lds16(gB3 + k0_, sb_ + 8192 + 12288 + lOF);                \
    }

    // Opaque asm: 12x ds_read_b128, no internal wait — completion confirmed
    // by the NEXT body's lgkmcnt(12). Early-clobber outputs (SSA -> MFMA
    // consumers can't be hoisted above the wait; rule #18).
#define READF(SR, aF, bF) {                                           \
        const unsigned aA_ = lsBase + (unsigned)(SR) * SLOT + aOff0;  \
        const unsigned bA_ = lsBase + (unsigned)(SR) * SLOT + bOff0;  \
        asm volatile(                                                 \
            "ds_read_b128 %0, %12 offset:0\n\t"                       \
            "ds_read_b128 %1, %12 offset:1024\n\t"                    \
            "ds_read_b128 %2, %12 offset:2048\n\t"                    \
            "ds_read_b128 %3, %12 offset:3072\n\t"                    \
            "ds_read_b128 %4, %13 offset:0\n\t"                       \
            "ds_read_b128 %5, %13 offset:1024\n\t"                    \
            "ds_read_b128 %6, %13 offset:2048\n\t"                    \
            "ds_read_b128 %7, %13 offset:3072\n\t"                    \
            "ds_read_b128 %8, %13 offset:4096\n\t"                    \
            "ds_read_b128 %9, %13 offset:5120\n\t"                    \
            "ds_read_b128 %10, %13 offset:6144\n\t"                   \
            "ds_read_b128 %11, %13 offset:7168"                       \
            : "=&v"(aF[0]), "=&v"(aF[1]), "=&v"(aF[2]), "=&v"(aF[3]), \
              "=&v"(bF[0]), "=&v"(bF[1]), "=&v"(bF[2]), "=&v"(bF[3]), \
              "=&v"(bF[4]), "=&v"(bF[5]), "=&v"(bF[6]), "=&v"(bF[7])  \
            : "v"(aA_), "v"(bA_));                                    \
    }

#define MFMAS(aF, bF) {                                               \
        __builtin_amdgcn_s_setprio(1);                                \
        _Pragma("unroll")                                             \
        for (int i_ = 0; i_ < 4; ++i_)                                \
            _Pragma("unroll")                                         \
            for (int j_ = 0; j_ < 8; ++j_)                            \
                iacc[i_][j_] = __builtin_amdgcn_mfma_i32_16x16x64_i8( \
                    aF[i_], bF[j_], iacc[i_][j_], 0, 0, 0);           \
        __builtin_amdgcn_s_setprio(0);                                \
    }

    // frag register double-buffer (constant-indexed arrays only)
    int32x4_t aX[4], bX[8], aY[4], bY[8];

    // BODY(s): STAGE(s+2) [depth-2, ring-3]; vmcnt(6) -> stage s+1 landed;
    // barrier publishes slot (s+1)%3; READF(s+1) into NXT (reads left in
    // flight); lgkmcnt(12) confirms slice-s reads; MFMA(CUR).
#define BODY(s, SS, SR, aC, bC, aN, bN) {                             \
        STAGE((s) + 2, SS);                                           \
        WAITVM(6);                                                    \
        BARRIER();                                                    \
        READF(SR, aN, bN);                                            \
        WAITLGKM(12);                                                 \
        MFMAS(aC, bC);                                                \
    }

    // ---- prologue: stages 0,1 (12 DMA); land 0; read frags(0) -> X ----
    STAGE(0, 0); STAGE(1, 1);
    WAITVM(6);                  // stage 0 landed (own-wave 6)
    BARRIER();                  // publish slot 0 (+ fws_s/wsf_s)
    READF(0, aX, bX);

    // ---- steady state: bodies 0..59, slots compile-time via unroll-6 ----
    for (int s = 0; s < NSLICE - 4; s += 6) {
        BODY(s + 0, 2, 1, aX, bX, aY, bY);
        BODY(s + 1, 0, 2, aY, bY, aX, bX);
        BODY(s + 2, 1, 0, aX, bX, aY, bY);
        BODY(s + 3, 2, 1, aY, bY, aX, bX);
        BODY(s + 4, 0, 2, aX, bX, aY, bY);
        BODY(s + 5, 1, 0, aY, bY, aX, bX);
    }
    // ---- tail: bodies 60..63 ----
    BODY(60, 2, 1, aX, bX, aY, bY);      // STAGE(62)
    BODY(61, 0, 2, aY, bY, aX, bX);      // STAGE(63)
    // body 62: no stage; land 63; read frags(63) -> Y; MFMA(62) on X
    WAITVM(0);
    BARRIER();
    READF(0, aY, bY);                    // slice 63 in slot 0
    WAITLGKM(12);
    MFMAS(aX, bX);
    // body 63: final MFMA on Y
    WAITLGKM(0);
    MFMAS(aY, bY);

    // --- epilogue: C/D layout col=lane&15, row=lquad*4+reg ---
    float fn[8], wf[8], bb[8];
    int ncol[8];
#pragma unroll
    for (int j = 0; j < 8; ++j) {
        const int ncl = wcl * 128 + j * 16 + lrow;
        ncol[j] = bn * BN + ncl;
        fn[j] = fws_s[ncl];
        wf[j] = wsf_s[ncl];
        bb[j] = bias[ncol[j]];
    }
    const int m0 = bm * BM + wr * 64;
#pragma unroll
    for (int i = 0; i < 4; ++i) {
#pragma unroll
        for (int r = 0; r < 4; ++r) {
            const int m = m0 + i * 16 + lquad * 4 + r;
            const float xs  = xscale[m];
            const float czp = xzpc[m];
            float* orow = out + (size_t)m * N_DIM;
#pragma unroll
            for (int j = 0; j < 8; ++j)
                orow[ncol[j]] = xs * (fn[j] * (float)iacc[i][j][r] + czp * wf[j]) + bb[j];
        }
    }
#undef BODY
#undef MFMAS
#undef READF
#undef STAGE
}

extern "C" void kernel_launch(void* const* d_in, const int* in_sizes, int n_in,
                              void* d_out, int out_size, void* d_ws, size_t ws_size,
                              hipStream_t stream) {
    const float* x     = (const float*)d_in[0];
    const int*   qw    = (const int*)d_in[1];
    const float* wsc   = (const float*)d_in[2];
    const int*   wzp   = (const int*)d_in[3];
    const float* bias  = (const float*)d_in[4];
    float* out = (float*)d_out;

    // workspace layout
    char* A8  = (char*)d_ws;                                   //  8 MiB
    char* Bt8 = A8 + (size_t)M_DIM * K_DIM;                    // 16 MiB
    float* xscale = (float*)(Bt8 + (size_t)N_DIM * K_DIM);     //  8 KiB
    float* xzpc   = xscale + M_DIM;                            //  8 KiB
    int*   Sw     = (int*)(xzpc + M_DIM);                      // 512 KiB

    prep_kernel<<<QUANT_BLOCKS + DEQ_BLOCKS, 256, 0, stream>>>(
        x, qw, wsc, wzp, A8, Bt8, xscale, xzpc, Sw);
    dim3 grid(N_DIM / BN, M_DIM / BM);
    gemm_kernel<<<grid, 256, 0, stream>>>(A8, Bt8, xscale, xzpc, wsc, Sw, bias, out);
}